// Round 3
// baseline (167.768 us; speedup 1.0000x reference)
//
#include <hip/hip_runtime.h>

// GraphAttentionLayer, B=8, N=1024, F_IN=64, HEADS=8, D=64.
// exp(leaky_relu(s_i + t_j)) factorizes across the LeakyReLU branch:
//   [s_i+t_j>0] e^{s_i} e^{t_j} + [s_i+t_j<=0] e^{0.01 s_i} e^{0.01 t_j}
// so softmax denominators (over i) and the weighted sum over j reduce to
// prefix sums over sorted s / sorted t.  O(N^2 D) -> O(N log N + N D).
//
// R3: k_inc + INC1/INC2 (65 MB round-trip) eliminated. k_mid counting-sorts
// the queries by rank and answers them DURING the chunk prefix walk, writing
// h' (hp) directly. 3 dispatches: k_wh -> k_mid -> k_out.

#define B_  8
#define N_  1024
#define H_  8
#define D_  64
#define BH_ 64
#define NCH 16          // chunks per (b,h) == waves per block
#define CLN 64          // ranks per chunk

// ---------------- Kernel A: Wh = h@W (row-blocked), s/t = Wh . a ----------
__global__ __launch_bounds__(256) void k_wh(
    const float* __restrict__ h, const float* __restrict__ W,
    const float* __restrict__ a,
    float* __restrict__ Wh, float* __restrict__ sArr, float* __restrict__ tArr) {
  __shared__ float hL[16 * 64];
  __shared__ float whL[16 * 512];
  __shared__ float aL[128];
  const int tid = threadIdx.x;
  const int row0 = blockIdx.x * 16;
  const int b = row0 >> 10;
  for (int i = tid; i < 16 * 64; i += 256) hL[i] = h[row0 * 64 + i];
  if (tid < 128) aL[tid] = a[tid];
  __syncthreads();

  float acc0[16], acc1[16];
#pragma unroll
  for (int r = 0; r < 16; ++r) { acc0[r] = 0.f; acc1[r] = 0.f; }
  for (int k = 0; k < 64; ++k) {
    const float w0 = W[k * 512 + tid];
    const float w1 = W[k * 512 + tid + 256];
#pragma unroll
    for (int r = 0; r < 16; ++r) {
      const float hv = hL[r * 64 + k];
      acc0[r] += hv * w0;
      acc1[r] += hv * w1;
    }
  }
  const int hh0 = tid >> 6, d0 = tid & 63;
  const int hh1 = (tid + 256) >> 6;
#pragma unroll
  for (int r = 0; r < 16; ++r) {
    const int n = (row0 + r) & (N_ - 1);
    whL[r * 512 + tid] = acc0[r];
    whL[r * 512 + tid + 256] = acc1[r];
    Wh[((b * H_ + hh0) * N_ + n) * D_ + d0] = acc0[r];
    Wh[((b * H_ + hh1) * N_ + n) * D_ + d0] = acc1[r];
  }
  __syncthreads();
  if (tid < 128) {
    const int r = tid >> 3, hh = tid & 7;
    const int n = (row0 + r) & (N_ - 1);
    float accS = 0.f, accT = 0.f;
    for (int jj = 0; jj < 64; ++jj) {
      const int d = (jj + tid) & 63;
      const float wv = whL[r * 512 + hh * 64 + d];
      accS += wv * aL[d];
      accT += wv * aL[64 + d];
    }
    sArr[(b * H_ + hh) * N_ + n] = accS;
    tArr[(b * H_ + hh) * N_ + n] = accT;
  }
}

// ---- Kernel B: per (b,h): sorts, scans, u/v, query counting-sort by rank,
//      chunk sums + offsets, prefix WALK with inline query emission -> hp ----
__global__ __launch_bounds__(1024) void k_mid(
    const float* __restrict__ sArr, const float* __restrict__ tArr,
    const float* __restrict__ Wh, float* __restrict__ hp) {
  __shared__ float sL[1024], tvL[1024];
  __shared__ int   tiL[1024];
  __shared__ float cum1L[1024], cum001L[1024];
  __shared__ float uL[1024], vL[1024];
  __shared__ float esQ[1024], es001Q[1024];
  __shared__ int   cntL[1025], startL[1025], qList[1024];
  __shared__ float cs1[NCH * 64], cs2[NCH * 64];
  __shared__ float wf1[16], wf2[16];
  __shared__ int   wi1[16];
  const int tid = threadIdx.x, lane = tid & 63, wv = tid >> 6;
  const int bh = blockIdx.x;
  const int b = bh >> 3, hh = bh & 7;

  const float orig_s = sArr[bh * N_ + tid];
  float sv_r = orig_s;
  float tv_r = tArr[bh * N_ + tid];
  int   ti_r = tid;
  cntL[tid] = 0;
  if (tid == 0) cntL[1024] = 0;

  // dual bitonic sort ascending; strides<64 via shfl, >=64 via LDS
  for (int size = 2; size <= 1024; size <<= 1) {
    for (int stride = size >> 1; stride > 0; stride >>= 1) {
      const bool up = ((tid & size) == 0);
      const bool lower = ((tid & stride) == 0);
      float psv, ptv; int pti;
      if (stride >= 64) {
        __syncthreads();
        sL[tid] = sv_r; tvL[tid] = tv_r; tiL[tid] = ti_r;
        __syncthreads();
        psv = sL[tid ^ stride]; ptv = tvL[tid ^ stride]; pti = tiL[tid ^ stride];
      } else {
        psv = __shfl_xor(sv_r, stride);
        ptv = __shfl_xor(tv_r, stride);
        pti = __shfl_xor(ti_r, stride);
      }
      const bool sameDir = (up == lower);
      const bool pLessS = (psv < sv_r);
      if (pLessS == sameDir) sv_r = psv;
      const bool pLessT = (ptv < tv_r) || (ptv == tv_r && pti < ti_r);
      if (pLessT == sameDir) { tv_r = ptv; ti_r = pti; }
    }
  }
  sL[tid] = sv_r; tvL[tid] = tv_r; tiL[tid] = ti_r;

  // inclusive scans of exp(s), exp(0.01 s): wave shfl-scan + cross-wave fixup
  float c1, c001;
  {
    float a1 = __expf(sv_r), a2 = __expf(0.01f * sv_r);
#pragma unroll
    for (int off = 1; off < 64; off <<= 1) {
      const float x1 = __shfl_up(a1, off);
      const float x2 = __shfl_up(a2, off);
      if (lane >= off) { a1 += x1; a2 += x2; }
    }
    if (lane == 63) { wf1[wv] = a1; wf2[wv] = a2; }
    __syncthreads();
    float o1 = 0.f, o2 = 0.f;
    for (int ww = 0; ww < 16; ++ww) {
      if (ww < wv) { o1 += wf1[ww]; o2 += wf2[ww]; }
    }
    c1 = a1 + o1; c001 = a2 + o2;
  }
  cum1L[tid] = c1; cum001L[tid] = c001;
  __syncthreads();
  const float totalHi = cum1L[1023];

  // per sorted-t rank: Z, u = e^t/Z, v = e^{0.01t}/Z
  {
    const float tj = tv_r;
    const float th = -tj;
    int lo = 0, hi = 1024;   // count of sorted-s <= th
    while (lo < hi) { const int mid = (lo + hi) >> 1; if (sL[mid] <= th) lo = mid + 1; else hi = mid; }
    const float S_lo = (lo > 0) ? cum001L[lo - 1] : 0.f;
    const float S_hi = totalHi - ((lo > 0) ? cum1L[lo - 1] : 0.f);
    const float et = __expf(tj), et001 = __expf(0.01f * tj);
    const float Z = et * S_hi + et001 * S_lo;
    uL[tid] = et / Z; vL[tid] = et001 / Z;
  }

  // query rank for row i=tid: count of t_j <= -s_i ; histogram by rank
  int rk;
  {
    const float th = -orig_s;
    int lo = 0, hi = 1024;
    while (lo < hi) { const int mid = (lo + hi) >> 1; if (tvL[mid] <= th) lo = mid + 1; else hi = mid; }
    rk = lo;
    atomicAdd(&cntL[rk], 1);
    esQ[tid] = __expf(orig_s);
    es001Q[tid] = __expf(0.01f * orig_s);
  }
  __syncthreads();

  // exclusive scan of cntL[0..1023] -> startL[0..1024]
  {
    const int cown = cntL[tid];
    int a = cown;
#pragma unroll
    for (int off = 1; off < 64; off <<= 1) {
      const int x = __shfl_up(a, off);
      if (lane >= off) a += x;
    }
    if (lane == 63) wi1[wv] = a;
    __syncthreads();
    int o = 0;
    for (int ww = 0; ww < 16; ++ww) {
      if (ww < wv) o += wi1[ww];
    }
    const int incl = a + o;
    startL[tid] = incl - cown;        // exclusive
    if (tid == 1023) startL[1024] = incl;
  }
  __syncthreads();
  cntL[tid] = 0;
  if (tid == 0) cntL[1024] = 0;
  __syncthreads();
  // scatter queries grouped by rank
  {
    const int pos = startL[rk] + atomicAdd(&cntL[rk], 1);
    qList[pos] = tid;
  }

  // chunk sums of u*Wh, v*Wh over sorted-t ranks (chunk = wave)
  {
    float s1 = 0.f, s2 = 0.f;
    for (int k2 = 0; k2 < CLN; ++k2) {
      const int k = wv * CLN + k2;
      const int j = tiL[k];
      const float w = Wh[(bh * N_ + j) * D_ + lane];
      s1 += uL[k] * w;
      s2 += vL[k] * w;
    }
    cs1[wv * 64 + lane] = s1; cs2[wv * 64 + lane] = s2;
  }
  __syncthreads();

  // per-wave exclusive chunk offsets + totals, then walk with emission
  float r1 = 0.f, r2 = 0.f, T1 = 0.f;
  for (int m = 0; m < NCH; ++m) {
    const float v1 = cs1[m * 64 + lane];
    if (m < wv) { r1 += v1; r2 += cs2[m * 64 + lane]; }
    T1 += v1;
  }
  for (int k2 = 0; k2 < CLN; ++k2) {
    const int K = wv * CLN + k2;
    const int qs = startL[K], qe = startL[K + 1];
    for (int q = qs; q < qe; ++q) {
      const int i = qList[q];
      hp[((b * N_ + i) << 9) + (hh << 6) + lane] =
          esQ[i] * (T1 - r1) + es001Q[i] * r2;
    }
    const int j = tiL[K];
    const float w = Wh[(bh * N_ + j) * D_ + lane];
    r1 += uL[K] * w;
    r2 += vL[K] * w;
  }
  if (wv == NCH - 1) {
    const int qs = startL[1024];
    for (int q = qs; q < 1024; ++q) {
      const int i = qList[q];
      hp[((b * N_ + i) << 9) + (hh << 6) + lane] =
          esQ[i] * (T1 - r1) + es001Q[i] * r2;
    }
  }
}

// ---- Kernel C: out[row] = hp[row] @ outW + outb (coalesced hp reads) -----
__global__ __launch_bounds__(512) void k_out(
    const float* __restrict__ hp,
    const float* __restrict__ outW, const float* __restrict__ outb,
    float* __restrict__ out) {
  __shared__ float hpL[16 * 512];
  __shared__ float part[8 * 8 * 64];
  const int tid = threadIdx.x;
  const int row0 = blockIdx.x * 16;
  for (int i = tid; i < 16 * 512; i += 512) hpL[i] = hp[row0 * 512 + i];
  __syncthreads();

  const int cc = tid & 63, p = tid >> 6;
  float acc[16];
#pragma unroll
  for (int r = 0; r < 16; ++r) acc[r] = 0.f;
  for (int k = p * 64; k < p * 64 + 64; ++k) {
    const float wvv = outW[k * 64 + cc];
#pragma unroll
    for (int r = 0; r < 16; ++r) acc[r] += hpL[r * 512 + k] * wvv;
  }
  for (int half = 0; half < 2; ++half) {
#pragma unroll
    for (int r = 0; r < 8; ++r) part[(p * 8 + r) * 64 + cc] = acc[half * 8 + r];
    __syncthreads();
    {
      const int r = tid >> 6, c2 = tid & 63;
      float ssum = 0.f;
#pragma unroll
      for (int p2 = 0; p2 < 8; ++p2) ssum += part[(p2 * 8 + r) * 64 + c2];
      out[(row0 + half * 8 + r) * 64 + c2] = outb[c2] + ssum;
    }
    __syncthreads();
  }
}

extern "C" void kernel_launch(void* const* d_in, const int* in_sizes, int n_in,
                              void* d_out, int out_size, void* d_ws, size_t ws_size,
                              hipStream_t stream) {
  const float* h    = (const float*)d_in[0];
  // d_in[1] = adj: all-ones, unused by the module
  const float* W    = (const float*)d_in[2];
  const float* a    = (const float*)d_in[3];
  const float* outW = (const float*)d_in[4];
  const float* outb = (const float*)d_in[5];
  float* out = (float*)d_out;

  float* ws   = (float*)d_ws;
  float* Wh   = ws;                                   // BH*N*D   (16 MB)
  float* sArr = Wh + (size_t)BH_ * N_ * D_;           // BH*N
  float* tArr = sArr + BH_ * N_;
  float* hpG  = tArr + BH_ * N_;                      // B*N*512  (16 MB)

  hipLaunchKernelGGL(k_wh,  dim3((B_ * N_) / 16), dim3(256), 0, stream,
                     h, W, a, Wh, sArr, tArr);
  hipLaunchKernelGGL(k_mid, dim3(BH_), dim3(1024), 0, stream,
                     sArr, tArr, Wh, hpG);
  hipLaunchKernelGGL(k_out, dim3((B_ * N_) / 16), dim3(512), 0, stream,
                     hpG, outW, outb, out);
}